// Round 11
// baseline (82.316 us; speedup 1.0000x reference)
//
#include <hip/hip_runtime.h>
#include <math.h>

namespace {
constexpr int NB = 16, NP = 2048, KNN = 32, CH1 = 6, CH2 = 32;
constexpr int QPB = 16;                 // queries per block (8 waves x 2)
constexpr int NBLK = NB * NP / QPB;     // 2048 knn blocks
constexpr float BN_EPS = 1e-5f;

// workspace byte offsets
constexpr size_t OFF_S1REP   = 0;      // double[8][12] replicated BN1 accum (768 B)
constexpr size_t OFF_STATS2L = 768;    // double[4][27] BN2 moment accum (864 B)
constexpr size_t OFF_SC1     = 1664;   // float[12]
constexpr size_t OFF_P       = 2048;                                // float[NB*NP*6]
constexpr size_t OFF_MINQ    = OFF_P + sizeof(float)*NB*NP*CH1;     // float[NB*NP*6]
}

typedef __attribute__((ext_vector_type(2))) float f32x2;

// packed fp32 (VOP3P, per-half IEEE RN — bit-identical to scalar mul/add)
__device__ __forceinline__ f32x2 pk_mul(f32x2 a, f32x2 b) {
  f32x2 d; asm("v_pk_mul_f32 %0, %1, %2" : "=v"(d) : "v"(a), "v"(b)); return d;
}
__device__ __forceinline__ f32x2 pk_add(f32x2 a, f32x2 b) {
  f32x2 d; asm("v_pk_add_f32 %0, %1, %2" : "=v"(d) : "v"(a), "v"(b)); return d;
}

// ---------------- DPP wave-64 reductions (VALU pipe, no LDS) ----------------
template <int C> __device__ __forceinline__ int dpp0i(int x) {
  return __builtin_amdgcn_update_dpp(0, x, C, 0xf, 0xf, true);
}
template <int C> __device__ __forceinline__ float dpp0f(float x) {
  return __uint_as_float((unsigned)__builtin_amdgcn_update_dpp(
      0, (int)__float_as_uint(x), C, 0xf, 0xf, true));
}
template <int C> __device__ __forceinline__ float dppInff(float x) {
  return __uint_as_float((unsigned)__builtin_amdgcn_update_dpp(
      0x7F800000, (int)__float_as_uint(x), C, 0xf, 0xf, false));
}
__device__ __forceinline__ int wave_isum_bcast(int x) {
  x += dpp0i<0x111>(x); x += dpp0i<0x112>(x); x += dpp0i<0x114>(x);
  x += dpp0i<0x118>(x); x += dpp0i<0x142>(x); x += dpp0i<0x143>(x);
  return __builtin_amdgcn_readlane(x, 63);
}
__device__ __forceinline__ float wave_fsum63(float x) {
  x += dpp0f<0x111>(x); x += dpp0f<0x112>(x); x += dpp0f<0x114>(x);
  x += dpp0f<0x118>(x); x += dpp0f<0x142>(x); x += dpp0f<0x143>(x);
  return x;
}
__device__ __forceinline__ float wave_fmin63(float x) {
  x = fminf(x, dppInff<0x111>(x)); x = fminf(x, dppInff<0x112>(x));
  x = fminf(x, dppInff<0x114>(x)); x = fminf(x, dppInff<0x118>(x));
  x = fminf(x, dppInff<0x142>(x)); x = fminf(x, dppInff<0x143>(x));
  return x;
}

#define BSEL(m, x, y) ((((x)) & (m)) | (((y)) & ~(m)))  // -> v_bfi

// One branchless radix round. Correct even after resolution (splitting a
// resolved bucket preserves ca==rem), so no freeze guards are needed.
#define RROUND(alive, below, rem, ca, plane)                  \
  { unsigned z_ = (alive) & ~(plane);                         \
    int c_ = wave_isum_bcast(__popc(z_));                     \
    bool t_ = (c_ >= (rem));                                  \
    below = t_ ? (below) : ((below) | z_);                    \
    alive = t_ ? z_ : ((alive) & (plane));                    \
    ca    = t_ ? c_ : (ca) - c_;                              \
    rem   = t_ ? (rem) : (rem) - c_; }

// J16 stage: split dd[32] into packed hi/lo half-planes (dd dies).
#define J16_SPLIT(dd, h, l)                                          \
  _Pragma("unroll") for (int g_ = 0; g_ < 16; ++g_) {                \
    h[g_] = __builtin_amdgcn_perm(dd[g_], dd[g_+16], 0x07060302u);   \
    l[g_] = __builtin_amdgcn_perm(dd[g_], dd[g_+16], 0x05040100u); }

// finish a 16-reg packed half: J8,4,2,1 -> a[i] = plane of its bit i (MSB first)
#define TR16(a)                                                      \
  _Pragma("unroll") for (int g_ = 0; g_ < 8; ++g_) {                 \
    unsigned hi_ = a[g_], lo_ = a[g_+8];                             \
    a[g_]   = __builtin_amdgcn_perm(hi_, lo_, 0x07030501u);          \
    a[g_+8] = __builtin_amdgcn_perm(hi_, lo_, 0x06020400u); }        \
  _Pragma("unroll") for (int g_ = 0; g_ < 8; ++g_) {                 \
    int k_ = (g_ >> 2)*8 + (g_ & 3);                                 \
    unsigned A_ = a[k_], B_ = a[k_+4];                               \
    a[k_]   = BSEL(0x0F0F0F0Fu, B_ >> 4, A_);                        \
    a[k_+4] = BSEL(0xF0F0F0F0u, A_ << 4, B_); }                      \
  _Pragma("unroll") for (int g_ = 0; g_ < 8; ++g_) {                 \
    int k_ = (g_ >> 1)*4 + (g_ & 1);                                 \
    unsigned A_ = a[k_], B_ = a[k_+2];                               \
    a[k_]   = BSEL(0x33333333u, B_ >> 2, A_);                        \
    a[k_+2] = BSEL(0xCCCCCCCCu, A_ << 2, B_); }                      \
  _Pragma("unroll") for (int g_ = 0; g_ < 8; ++g_) {                 \
    int k_ = g_*2;                                                   \
    unsigned A_ = a[k_], B_ = a[k_+1];                               \
    a[k_]   = BSEL(0x55555555u, B_ >> 1, A_);                        \
    a[k_+1] = BSEL(0xAAAAAAAAu, A_ << 1, B_); }

// exact index-order tie-break among bit-identical distances (j = v*64+lane)
#define TIEBREAK(alive, sel, rem)                                    \
  for (int v_ = 0; v_ < 32; ++v_) {                                  \
    if ((rem) <= 0) break;                                           \
    bool mine_ = ((alive) >> v_) & 1;                                \
    unsigned long long mb_ = __ballot(mine_);                        \
    int c_ = __popcll(mb_);                                          \
    if (c_ <= (rem)) { if (mine_) (sel) |= 1u << v_; (rem) -= c_; }  \
    else {                                                           \
      if (mine_ && (int)__popcll(mb_ & ((1ull << lane) - 1)) < (rem))\
        (sel) |= 1u << v_;                                           \
      (rem) = 0;                                                     \
    }                                                                \
  }

// Fused: pq + KNN select + per-query min(q) + BN1 replicated-atomic partials.
// TWO queries per wave: independent radix chains interleave (ILP hides the
// DPP-chain latency that bounded r10), and each LDS chunk read serves both
// queries' distance math. Candidate mapping j = v*64 + lane (conflict-free
// chunked-SoA layout proven in r10: 206K conflicts only).
__global__ __launch_bounds__(512, 4) void knn_kernel(const float* __restrict__ x,
                                                     const float* __restrict__ W1,
                                                     const float* __restrict__ b1,
                                                     float* __restrict__ pout,
                                                     float* __restrict__ minq,
                                                     double* __restrict__ s1rep) {
  __shared__ float4 XC[512], YC[512], ZC[512], WC[512];  // 32 KiB chunked SoA
  __shared__ float red[12][8];
  const int lane = threadIdx.x & 63;
  const int w    = threadIdx.x >> 6;
  const int qiA  = blockIdx.x * QPB + w * 2;   // 16 | 2048 -> same batch per block
  const int qiB  = qiA + 1;
  const int b    = qiA >> 11;
  const int nA   = qiA & (NP - 1), nB = qiB & (NP - 1);

  const float* xb = x + (size_t)b * NP * 3;
  {
    const int t = threadIdx.x;               // slot t: points 256*(t>>6)+64k+(t&63)
    const int g0 = t >> 6, ls = t & 63;
    float xx[4], yy[4], zz[4], ww[4];
#pragma unroll
    for (int k = 0; k < 4; ++k) {
      const float* pp = xb + (g0*256 + k*64 + ls) * 3;
      float a0 = pp[0], a1 = pp[1], a2 = pp[2];
      xx[k] = a0; yy[k] = a1; zz[k] = a2;
      ww[k] = __fadd_rn(__fadd_rn(__fmul_rn(a0,a0), __fmul_rn(a1,a1)), __fmul_rn(a2,a2));
    }
    XC[t] = (float4){xx[0], xx[1], xx[2], xx[3]};
    YC[t] = (float4){yy[0], yy[1], yy[2], yy[3]};
    ZC[t] = (float4){zz[0], zz[1], zz[2], zz[3]};
    WC[t] = (float4){ww[0], ww[1], ww[2], ww[3]};
  }
  __syncthreads();

  const float* Xs = (const float*)XC;
  const float* Ys = (const float*)YC;
  const float* Zs = (const float*)ZC;
  const float* Ws = (const float*)WC;

  // query coords (wave-uniform broadcast reads); point n -> v=n>>6, lane=n&63
  const int vqA = nA >> 6, lqA = nA & 63;
  const int qidxA = (((vqA >> 2) << 6) | lqA) * 4 + (vqA & 3);
  const float qxA = Xs[qidxA], qyA = Ys[qidxA], qzA = Zs[qidxA], qwA = Ws[qidxA];
  const int vqB = nB >> 6, lqB = nB & 63;
  const int qidxB = (((vqB >> 2) << 6) | lqB) * 4 + (vqB & 3);
  const float qxB = Xs[qidxB], qyB = Ys[qidxB], qzB = Zs[qidxB], qwB = Ws[qidxB];
  const f32x2 qxA2 = {qxA,qxA}, qyA2 = {qyA,qyA}, qzA2 = {qzA,qzA}, qwA2 = {qwA,qwA};
  const f32x2 qxB2 = {qxB,qxB}, qyB2 = {qyB,qyB}, qzB2 = {qzB,qzB}, qwB2 = {qwB,qwB};

  // distances for BOTH queries from ONE set of chunk reads.
  // Bit-exact vs reference ((x*x+y*y)+z*z ; (sqi+sqj) - (dot+dot)); d>=0 so raw
  // float bits order. dX[31-v] = bits of candidate v*64+lane.
  unsigned dA[32], dB[32];
#pragma unroll
  for (int g = 0; g < 8; ++g) {
    const int cs = g*64 + lane;
    float4 X = XC[cs], Y = YC[cs], Z = ZC[cs], Wv = WC[cs];
    f32x2 x01 = {X.x,X.y}, y01 = {Y.x,Y.y}, z01 = {Z.x,Z.y}, w01 = {Wv.x,Wv.y};
    f32x2 x23 = {X.z,X.w}, y23 = {Y.z,Y.w}, z23 = {Z.z,Z.w}, w23 = {Wv.z,Wv.w};
    {
      f32x2 dot0 = pk_add(pk_add(pk_mul(qxA2,x01), pk_mul(qyA2,y01)), pk_mul(qzA2,z01));
      f32x2 dot1 = pk_add(pk_add(pk_mul(qxA2,x23), pk_mul(qyA2,y23)), pk_mul(qzA2,z23));
      f32x2 ss0 = pk_add(qwA2, w01), ss1 = pk_add(qwA2, w23);
      f32x2 dt0 = pk_add(dot0, dot0), dt1 = pk_add(dot1, dot1);
      dA[31-(4*g+0)] = __float_as_uint(__fsub_rn(ss0.x, dt0.x));
      dA[31-(4*g+1)] = __float_as_uint(__fsub_rn(ss0.y, dt0.y));
      dA[31-(4*g+2)] = __float_as_uint(__fsub_rn(ss1.x, dt1.x));
      dA[31-(4*g+3)] = __float_as_uint(__fsub_rn(ss1.y, dt1.y));
    }
    {
      f32x2 dot0 = pk_add(pk_add(pk_mul(qxB2,x01), pk_mul(qyB2,y01)), pk_mul(qzB2,z01));
      f32x2 dot1 = pk_add(pk_add(pk_mul(qxB2,x23), pk_mul(qyB2,y23)), pk_mul(qzB2,z23));
      f32x2 ss0 = pk_add(qwB2, w01), ss1 = pk_add(qwB2, w23);
      f32x2 dt0 = pk_add(dot0, dot0), dt1 = pk_add(dot1, dot1);
      dB[31-(4*g+0)] = __float_as_uint(__fsub_rn(ss0.x, dt0.x));
      dB[31-(4*g+1)] = __float_as_uint(__fsub_rn(ss0.y, dt0.y));
      dB[31-(4*g+2)] = __float_as_uint(__fsub_rn(ss1.x, dt1.x));
      dB[31-(4*g+3)] = __float_as_uint(__fsub_rn(ss1.y, dt1.y));
    }
  }

  unsigned hA[16], lA[16], hB[16], lB[16];
  J16_SPLIT(dA, hA, lA);
  TR16(hA);                 // hA[i] = plane of distance bit (31-i)
  J16_SPLIT(dB, hB, lB);
  TR16(hB);

  // interleaved branchless radix on bits 30..16 for both queries
  unsigned aliveA = 0xFFFFFFFFu, belowA = 0u, aliveB = 0xFFFFFFFFu, belowB = 0u;
  int remA = KNN, caA = 2048, remB = KNN, caB = 2048;
#pragma unroll
  for (int i = 1; i <= 7; ++i) {
    RROUND(aliveA, belowA, remA, caA, hA[i]);
    RROUND(aliveB, belowB, remB, caB, hB[i]);
  }
#pragma unroll
  for (int i = 8; i <= 15; ++i) {
    if (caA != remA || caB != remB) {       // wave-uniform skip once both resolved
      RROUND(aliveA, belowA, remA, caA, hA[i]);
      RROUND(aliveB, belowB, remB, caB, hB[i]);
    }
  }
  unsigned selA, selB;
  if (__builtin_expect((caA == remA) && (caB == remB), 1)) {
    selA = belowA | aliveA;
    selB = belowB | aliveB;
  } else {
    TR16(lA);               // lA[i] = plane of distance bit (15-i)
    TR16(lB);
#pragma unroll
    for (int i = 0; i < 16; ++i) {
      if (caA != remA || caB != remB) {
        RROUND(aliveA, belowA, remA, caA, lA[i]);
        RROUND(aliveB, belowB, remB, caB, lB[i]);
      }
    }
    selA = belowA;
    if (caA == remA) selA |= aliveA; else { TIEBREAK(aliveA, selA, remA); }
    selB = belowB;
    if (caB == remB) selB |= aliveB; else { TIEBREAK(aliveB, selB, remB); }
  }

  // gather: sum/sumsq/min of q_j over selected (scalar chunk reads, ~2-way max)
  float w3[CH1], w4[CH1], w5[CH1];
#pragma unroll
  for (int c = 0; c < CH1; ++c) { w3[c]=W1[3*CH1+c]; w4[c]=W1[4*CH1+c]; w5[c]=W1[5*CH1+c]; }
  float sqA[CH1], sqqA[CH1], mnA[CH1], sqB[CH1], sqqB[CH1], mnB[CH1];
#pragma unroll
  for (int c = 0; c < CH1; ++c) {
    sqA[c] = 0.f; sqqA[c] = 0.f; mnA[c] = INFINITY;
    sqB[c] = 0.f; sqqB[c] = 0.f; mnB[c] = INFINITY;
  }
  unsigned m = selA;
  while (m) {
    int v = __builtin_ctz(m); m &= m - 1;
    int idx = (((v >> 2) << 6) | lane) * 4 + (v & 3);
    float px_ = Xs[idx], py_ = Ys[idx], pz_ = Zs[idx];
#pragma unroll
    for (int c = 0; c < CH1; ++c) {
      float qv = px_*w3[c] + py_*w4[c] + pz_*w5[c];   // contraction OK here
      sqA[c] += qv; sqqA[c] += qv*qv; mnA[c] = fminf(mnA[c], qv);
    }
  }
  m = selB;
  while (m) {
    int v = __builtin_ctz(m); m &= m - 1;
    int idx = (((v >> 2) << 6) | lane) * 4 + (v & 3);
    float px_ = Xs[idx], py_ = Ys[idx], pz_ = Zs[idx];
#pragma unroll
    for (int c = 0; c < CH1; ++c) {
      float qv = px_*w3[c] + py_*w4[c] + pz_*w5[c];
      sqB[c] += qv; sqqB[c] += qv*qv; mnB[c] = fminf(mnB[c], qv);
    }
  }

  // p_i for both queries (uniform across lanes)
  float pvA[CH1], pvB[CH1];
#pragma unroll
  for (int c = 0; c < CH1; ++c) {
    float qvA = qxA*w3[c] + qyA*w4[c] + qzA*w5[c];
    pvA[c] = b1[c] + qxA*W1[c] + qyA*W1[CH1+c] + qzA*W1[2*CH1+c] + qvA;
    float qvB = qxB*w3[c] + qyB*w4[c] + qzB*w5[c];
    pvB[c] = b1[c] + qxB*W1[c] + qyB*W1[CH1+c] + qzB*W1[2*CH1+c] + qvB;
  }

#pragma unroll
  for (int c = 0; c < CH1; ++c) {
    float sA  = wave_fsum63(sqA[c]);
    float s2A = wave_fsum63(sqqA[c]);
    float mmA = wave_fmin63(mnA[c]);
    float sB  = wave_fsum63(sqB[c]);
    float s2B = wave_fsum63(sqqB[c]);
    float mmB = wave_fmin63(mnB[c]);
    if (lane == 63) {
      minq[qiA*CH1 + c] = mmA;
      minq[qiB*CH1 + c] = mmB;
      float hsA = fmaf(32.f, pvA[c], -sA);
      float hqA = fmaf(32.f, pvA[c]*pvA[c], fmaf(-2.f*pvA[c], sA, s2A));
      float hsB = fmaf(32.f, pvB[c], -sB);
      float hqB = fmaf(32.f, pvB[c]*pvB[c], fmaf(-2.f*pvB[c], sB, s2B));
      red[c][w]       = hsA + hsB;
      red[CH1 + c][w] = hqA + hqB;
    }
  }
  if (lane == 0) {
#pragma unroll
    for (int c = 0; c < CH1; ++c) {
      pout[qiA*CH1 + c] = pvA[c];
      pout[qiB*CH1 + c] = pvB[c];
    }
  }
  __syncthreads();
  if (threadIdx.x < 12) {
    float s = 0.f;
#pragma unroll
    for (int ww2 = 0; ww2 < 8; ++ww2) s += red[threadIdx.x][ww2];
    atomicAdd(s1rep + (blockIdx.x & 7) * 12 + threadIdx.x, (double)s);
  }
}

// stage2: derive sc1 (block 0 publishes), compute me per query, accumulate the
// 27 BN2 moments (Sme[6] + upper-tri M[21]); y-stats derive from them linearly.
__global__ __launch_bounds__(256) void stage2_kernel(const float* __restrict__ p,
                                                     const float* __restrict__ minq,
                                                     const double* __restrict__ s1rep,
                                                     const float* __restrict__ gamma1,
                                                     const float* __restrict__ beta1,
                                                     float* __restrict__ sc1g,
                                                     double* __restrict__ stats2L) {
  __shared__ double tot1[12];
  __shared__ float sc1s[12];
  __shared__ float acc[4][27];
  const int t = threadIdx.x;
  if (t < 12) {
    double s = 0.0;
#pragma unroll
    for (int r = 0; r < 8; ++r) s += s1rep[r*12 + t];
    tot1[t] = s;
  }
  __syncthreads();
  if (t < CH1) {
    double cnt  = (double)NB * NP * KNN;
    double mean = tot1[t] / cnt;
    double var  = tot1[CH1 + t] / cnt - mean * mean;
    float scale = gamma1[t] / sqrtf((float)var + BN_EPS);
    sc1s[t] = scale; sc1s[CH1 + t] = beta1[t] - (float)mean * scale;
  }
  __syncthreads();
  if (blockIdx.x == 0 && t < 12) sc1g[t] = sc1s[t];

  const int qi = blockIdx.x * 256 + t;
  const int w = t >> 6, lane = t & 63;
  float me[CH1];
#pragma unroll
  for (int c = 0; c < CH1; ++c) {
    float v = fmaf(sc1s[c], p[qi*CH1 + c] - minq[qi*CH1 + c], sc1s[CH1 + c]);
    me[c] = v > 0.f ? v : expm1f(v);
  }
  float vals[27];
#pragma unroll
  for (int c = 0; c < CH1; ++c) vals[c] = me[c];
  {
    int id = 6;
#pragma unroll
    for (int c = 0; c < CH1; ++c)
#pragma unroll
      for (int d = c; d < CH1; ++d) { vals[id] = me[c]*me[d]; ++id; }
  }
#pragma unroll
  for (int k = 0; k < 27; ++k) {
    float s = wave_fsum63(vals[k]);
    if (lane == 63) acc[w][k] = s;
  }
  __syncthreads();
  if (t < 27)
    atomicAdd(stats2L + (blockIdx.x & 3) * 27 + t,
              (double)((acc[0][t] + acc[1][t]) + (acc[2][t] + acc[3][t])));
}

// final: derive sc2 per block from the 27 moments, recompute y, BN2 + ELU.
__global__ __launch_bounds__(256) void out_kernel(const float* __restrict__ p,
                                                  const float* __restrict__ minq,
                                                  const float* __restrict__ sc1,
                                                  const float* __restrict__ W2,
                                                  const float* __restrict__ b2,
                                                  const double* __restrict__ stats2L,
                                                  const float* __restrict__ gamma2,
                                                  const float* __restrict__ beta2,
                                                  float* __restrict__ out) {
  __shared__ float m2[27];
  __shared__ float me_lds[8][CH1];
  __shared__ float s2s[CH2], s2h[CH2];
  const int t = threadIdx.x;
  if (t < 27)
    m2[t] = (float)(((stats2L[t] + stats2L[27+t]) + (stats2L[54+t] + stats2L[81+t])));
  const int qbase = blockIdx.x * 8;
  if (t >= 64 && t < 112) {
    int qs = (t - 64) / 6, c = (t - 64) % 6;
    int qi = qbase + qs;
    float v = fmaf(sc1[c], p[qi*CH1 + c] - minq[qi*CH1 + c], sc1[CH1 + c]);
    me_lds[qs][c] = v > 0.f ? v : expm1f(v);
  }
  __syncthreads();
  if (t < CH2) {
    float wv[CH1];
#pragma unroll
    for (int c = 0; c < CH1; ++c) wv[c] = W2[c*CH2 + t];
    float sy = 0.f;
#pragma unroll
    for (int c = 0; c < CH1; ++c) sy = fmaf(wv[c], m2[c], sy);
    float sy2 = 0.f;
    {
      int id = 6;
#pragma unroll
      for (int c = 0; c < CH1; ++c)
#pragma unroll
        for (int d = c; d < CH1; ++d) {
          float coef = (c == d) ? wv[c]*wv[c] : 2.f*wv[c]*wv[d];
          sy2 = fmaf(coef, m2[id], sy2); ++id;
        }
    }
    const double N = (double)NB * NP;
    double bo   = (double)b2[t];
    double mean = ((double)sy + N*bo) / N;
    double Ey2  = ((double)sy2 + 2.0*bo*(double)sy + N*bo*bo) / N;
    double var  = Ey2 - mean*mean;
    float scale = gamma2[t] / sqrtf((float)var + BN_EPS);
    s2s[t] = scale; s2h[t] = beta2[t] - (float)mean * scale;
  }
  __syncthreads();
  const int qs = t >> 5, o = t & 31;
  const int qi = qbase + qs;
  float y = b2[o];
#pragma unroll
  for (int c = 0; c < CH1; ++c) y = fmaf(me_lds[qs][c], W2[c*CH2 + o], y);
  float r = fmaf(s2s[o], y, s2h[o]);
  out[(size_t)qi*CH2 + o] = r > 0.f ? r : expm1f(r);
}

extern "C" void kernel_launch(void* const* d_in, const int* in_sizes, int n_in,
                              void* d_out, int out_size, void* d_ws, size_t ws_size,
                              hipStream_t stream) {
  const float* x      = (const float*)d_in[0];
  const float* W1     = (const float*)d_in[1];
  const float* b1     = (const float*)d_in[2];
  const float* gamma1 = (const float*)d_in[3];
  const float* beta1  = (const float*)d_in[4];
  const float* W2     = (const float*)d_in[5];
  const float* b2     = (const float*)d_in[6];
  const float* gamma2 = (const float*)d_in[7];
  const float* beta2  = (const float*)d_in[8];
  float* out = (float*)d_out;
  char* ws = (char*)d_ws;

  double* s1rep   = (double*)(ws + OFF_S1REP);
  double* stats2L = (double*)(ws + OFF_STATS2L);
  float* sc1  = (float*)(ws + OFF_SC1);
  float* p    = (float*)(ws + OFF_P);
  float* minq = (float*)(ws + OFF_MINQ);

  hipMemsetAsync(ws, 0, 1664, stream);  // zero BN stat accumulators

  knn_kernel   <<<dim3(NBLK),       dim3(512), 0, stream>>>(x, W1, b1, p, minq, s1rep);
  stage2_kernel<<<dim3(NB*NP/256),  dim3(256), 0, stream>>>(p, minq, s1rep, gamma1, beta1,
                                                            sc1, stats2L);
  out_kernel   <<<dim3(NB*NP/8),    dim3(256), 0, stream>>>(p, minq, sc1, W2, b2,
                                                            stats2L, gamma2, beta2, out);
}